// Round 5
// baseline (4415.371 us; speedup 1.0000x reference)
//
#include <hip/hip_runtime.h>

typedef unsigned short u16;
typedef __attribute__((ext_vector_type(8))) __bf16 bfrag;
typedef __attribute__((ext_vector_type(4))) float f32x4;

static __device__ __forceinline__ f32x4 MFMA(bfrag a, bfrag b, f32x4 c) {
  return __builtin_amdgcn_mfma_f32_16x16x32_bf16(a, b, c, 0, 0, 0);
}

// float -> bf16 (RNE)
static __device__ __forceinline__ u16 f2b(float f) {
  union { float f; unsigned u; } v; v.f = f;
  unsigned r = (v.u + 0x7fffu + ((v.u >> 16) & 1u)) >> 16;
  return (u16)r;
}
static __device__ __forceinline__ float ssig(float x) { return 1.f / (1.f + __expf(-x)); }
static __device__ __forceinline__ float stanh(float x) { return 1.f - 2.f / (__expf(2.f * x) + 1.f); }

// ---------------------------------------------------------------------------
// prep: bf16 casts + gate-retiled decode weights.
// Decode: MFMA col n = g16*64 + gate*16 + m15 <-> source row gate*256 + g16*16 + m15.
// Predictor: n' = hcol*4 + gate (cases 12-14).
// ---------------------------------------------------------------------------
struct PrepArgs {
  const float *x, *W1, *W2, *W3, *Wh1, *Wc1, *Wx1, *Wh2, *Wc2, *Wx2;
  const float *rWih, *rWhh, *rbih, *rbhh, *pWih, *pWhh, *pbih, *pbhh;
  u16 *Xbf, *W1b, *W2b, *W3b, *Wh1b, *Wc1b, *Wx1b, *Wh2b, *Wc2b, *Wx2b;
  u16 *WcR, *WcatR, *pWR, *pWhhR;
  float *rbR, *pbR;
};

__global__ __launch_bounds__(256) void prep(PrepArgs p) {
  const int tid0 = blockIdx.x * 256 + threadIdx.x;
  const int stride = gridDim.x * 256;
  switch (blockIdx.y) {
    case 0: for (int i = tid0; i < 131072; i += stride) p.Xbf[i] = f2b(p.x[i]); break;
    case 1: for (int i = tid0; i < 65536;  i += stride) p.W1b[i] = f2b(p.W1[i]); break;
    case 2: for (int i = tid0; i < 262144; i += stride) p.W2b[i] = f2b(p.W2[i]); break;
    case 3: for (int i = tid0; i < 262144; i += stride) p.W3b[i] = f2b(p.W3[i]); break;
    case 4: for (int i = tid0; i < 262144; i += stride) p.Wh1b[i] = f2b(p.Wh1[i]); break;
    case 5: for (int i = tid0; i < 262144; i += stride) p.Wc1b[i] = f2b(p.Wc1[i]); break;
    case 6: for (int i = tid0; i < 262144; i += stride) p.Wx1b[i] = f2b(p.Wx1[i]); break;
    case 7: for (int i = tid0; i < 131072; i += stride) p.Wh2b[i] = f2b(p.Wh2[i]); break;
    case 8: for (int i = tid0; i < 131072; i += stride) p.Wc2b[i] = f2b(p.Wc2[i]); break;
    case 9: for (int i = tid0; i < 131072; i += stride) p.Wx2b[i] = f2b(p.Wx2[i]); break;
    case 10: // decode weights: combined (steps>=1) and concat (step 0), gate-retiled
      for (int i = tid0; i < 262144; i += stride) {
        int n = i >> 8, k = i & 255;
        int srow = (((n >> 4) & 3) << 8) + ((n >> 6) << 4) + (n & 15);
        float a = p.rWih[srow * 256 + k], b = p.rWhh[srow * 256 + k];
        p.WcR[i] = f2b(a + b);
        p.WcatR[n * 512 + k] = f2b(a);
        p.WcatR[n * 512 + 256 + k] = f2b(b);
      }
      break;
    case 11:
      for (int i = tid0; i < 1024; i += stride) {
        int srow = (((i >> 4) & 3) << 8) + ((i >> 6) << 4) + (i & 15);
        p.rbR[i] = p.rbih[srow] + p.rbhh[srow];
      }
      break;
    case 12:
      for (int i = tid0; i < 32768; i += stride) {
        int n2 = i >> 8, k = i & 255;
        int srow = ((n2 & 3) << 5) + (n2 >> 2);
        p.pWR[i] = f2b(p.pWih[srow * 256 + k]);
      }
      break;
    case 13:
      for (int i = tid0; i < 4096; i += stride) {
        int n2 = i >> 5, k = i & 31;
        int srow = ((n2 & 3) << 5) + (n2 >> 2);
        p.pWhhR[i] = f2b(p.pWhh[srow * 32 + k]);
      }
      break;
    case 14:
      for (int i = tid0; i < 128; i += stride) {
        int srow = ((i & 3) << 5) + (i >> 2);
        p.pbR[i] = p.pbih[srow] + p.pbhh[srow];
      }
      break;
  }
}

// ---------------------------------------------------------------------------
// gemm_act: Y[1024,N] = act(X[1024,K] @ W[N,K]^T + bias), bf16 in, fp32 acc.
// ---------------------------------------------------------------------------
__global__ __launch_bounds__(256) void gemm_act(
    const u16* __restrict__ X, const u16* __restrict__ W,
    const float* __restrict__ bias,
    u16* __restrict__ Yb, float* __restrict__ Yf,
    int K, int ldo, int coloff, int leaky) {
  const int rt = blockIdx.x, ct = blockIdx.y;
  const int lane = threadIdx.x & 63, wave = threadIdx.x >> 6;
  const int m15 = lane & 15, q = lane >> 4, kq = q * 8;
  const int row = rt * 64 + wave * 16 + m15;
  f32x4 acc[4] = {};
  const u16* xp = X + (size_t)row * K + kq;
  for (int k0 = 0; k0 < K; k0 += 32) {
    bfrag a = *(const bfrag*)(xp + k0);
#pragma unroll
    for (int nt = 0; nt < 4; nt++) {
      const u16* wp = W + (size_t)(ct * 64 + nt * 16 + m15) * K + k0 + kq;
      acc[nt] = MFMA(a, *(const bfrag*)wp, acc[nt]);
    }
  }
#pragma unroll
  for (int nt = 0; nt < 4; nt++) {
    int col = ct * 64 + nt * 16 + m15;
    float bv = bias[col];
#pragma unroll
    for (int r = 0; r < 4; r++) {
      int orow = rt * 64 + wave * 16 + q * 4 + r;
      float v = acc[nt][r] + bv;
      if (leaky) v = v >= 0.f ? v : 0.2f * v;
      if (Yb) Yb[(size_t)orow * ldo + coloff + col] = f2b(v);
      else    Yf[(size_t)orow * ldo + coloff + col] = v;
    }
  }
}

// ---------------------------------------------------------------------------
// decode_step: step 0 only (K=512 concat input), gate-retiled columns.
// ---------------------------------------------------------------------------
__global__ __launch_bounds__(256) void decode_step(
    const u16* __restrict__ A, const u16* __restrict__ W,
    const float* __restrict__ rb,
    float* __restrict__ C, u16* __restrict__ Hout, int K) {
  __shared__ float g[64][128];
  const int rt = blockIdx.x, cg = blockIdx.y;
  const int lane = threadIdx.x & 63, wave = threadIdx.x >> 6;
  const int m15 = lane & 15, q = lane >> 4, kq = q * 8;
  const int row = rt * 64 + wave * 16 + m15;
  f32x4 acc[8] = {};
  const u16* ap = A + (size_t)row * K + kq;
  for (int k0 = 0; k0 < K; k0 += 32) {
    bfrag a = *(const bfrag*)(ap + k0);
#pragma unroll
    for (int nt = 0; nt < 8; nt++) {
      const u16* wp = W + (size_t)(cg * 128 + nt * 16 + m15) * K + k0 + kq;
      acc[nt] = MFMA(a, *(const bfrag*)wp, acc[nt]);
    }
  }
#pragma unroll
  for (int nt = 0; nt < 8; nt++)
#pragma unroll
    for (int r = 0; r < 4; r++)
      g[wave * 16 + q * 4 + r][nt * 16 + m15] = acc[nt][r];
  __syncthreads();
  for (int t = threadIdx.x; t < 2048; t += 256) {
    int rl = t >> 5, hc = t & 31;
    int grow = rt * 64 + rl, gcol = cg * 32 + hc;
    int base = ((hc >> 4) << 6) + (hc & 15);
    float gi = g[rl][base +  0] + rb[cg * 128 + base +  0];
    float gf = g[rl][base + 16] + rb[cg * 128 + base + 16];
    float gg = g[rl][base + 32] + rb[cg * 128 + base + 32];
    float go = g[rl][base + 48] + rb[cg * 128 + base + 48];
    size_t ci = (size_t)grow * 256 + gcol;
    float c = C[ci];
    float cn = ssig(gf) * c + ssig(gi) * stanh(gg);
    float hn = ssig(go) * stanh(cn);
    C[ci] = cn;
    Hout[ci] = f2b(hn);
  }
}

// ---------------------------------------------------------------------------
// decode_pred: fused decode steps 1..127 + predictor steps 0..127.
// 128 blocks x 512 thr. group=blk>>1 (16 rows), half=blk&1 (128 of 256 hcols).
// All decode weights register-resident (128 VGPR/wave). Per step, halves
// exchange h via global ping-pong + device-scope flag handshake. Predictor
// consumes h_s straight from LDS; softmax/sigmoid epilogue writes d_out.
// OUTS (128 MB traffic) and the separate predictor kernel are eliminated.
// ---------------------------------------------------------------------------
__global__ __launch_bounds__(512, 2) void decode_pred(
    const u16* __restrict__ W,      // WcR [1024][256] gate-retiled
    const float* __restrict__ rb,   // rbR [1024]
    const float* __restrict__ C0,   // CB  [1024][256] (c after step 0)
    const u16* __restrict__ H0,     // OUTS0 [1024][256] (h_0)
    const u16* __restrict__ pW,     // pWR  [128][256]
    const u16* __restrict__ pWhh,   // pWhhR [128][32]
    const float* __restrict__ pb,   // pbR [128]
    u16* __restrict__ Hx,           // [128 blk][2 parity][16][128]
    int* __restrict__ flags,        // [128]
    float* __restrict__ out) {      // [1024][128][32]
  __shared__ u16 hbuf[2][16][264];     // 16.9 KB, full h rows
  __shared__ float gbuf[8][16][20];    // 10.2 KB, per-wave pred transpose
  __shared__ u16 hp[2][16][40];        // 2.5 KB, pred hidden state
  __shared__ float ys[16][36];         // 2.3 KB
  __shared__ float smv[16], siv[16];
  const int tid = threadIdx.x;
  const int w = tid >> 6, lane = tid & 63;
  const int m15 = lane & 15, q = lane >> 4;
  const int blk = blockIdx.x, half = blk & 1, partner = blk ^ 1;
  const int rowg = (blk >> 1) * 16;
  const int hcL = w * 16 + m15;            // local hcol 0..127
  const int hcG = half * 128 + hcL;        // global hcol
  const int g16 = half * 8 + w;            // 16-hcol group index

  // ---- init LDS: h_0 full rows; zero pred state ----
  {
    int r = tid >> 5, c = (tid & 31) * 8;
    *(bfrag*)(&hbuf[0][0][0] + r * 264 + c) = *(const bfrag*)(H0 + (size_t)(rowg + r) * 256 + c);
  }
  for (int i = tid; i < 2 * 16 * 40; i += 512) (&hp[0][0][0])[i] = 0;

  // ---- per-lane state & register-resident weights ----
  float cst[4];
#pragma unroll
  for (int r = 0; r < 4; r++)
    cst[r] = C0[(size_t)(rowg + q * 4 + r) * 256 + hcG];
  const float rbv0 = rb[g16 * 64 +  0 + m15], rbv1 = rb[g16 * 64 + 16 + m15];
  const float rbv2 = rb[g16 * 64 + 32 + m15], rbv3 = rb[g16 * 64 + 48 + m15];

  const u16* wb = W + (size_t)(g16 * 64 + m15) * 256 + q * 8;
  bfrag WDi[8], WDf[8], WDg[8], WDo[8];
#pragma unroll
  for (int kt = 0; kt < 8; kt++) {
    WDi[kt] = *(const bfrag*)(wb + kt * 32);
    WDf[kt] = *(const bfrag*)(wb + 4096 + kt * 32);
    WDg[kt] = *(const bfrag*)(wb + 8192 + kt * 32);
    WDo[kt] = *(const bfrag*)(wb + 12288 + kt * 32);
  }
  bfrag WP[8], WPH;
#pragma unroll
  for (int kt = 0; kt < 8; kt++)
    WP[kt] = *(const bfrag*)(pW + (size_t)(w * 16 + m15) * 256 + kt * 32 + q * 8);
  WPH = *(const bfrag*)(pWhh + (size_t)(w * 16 + m15) * 32 + q * 8);

  const int hloc = lane >> 4;              // pred hcol-in-wave 0..3
  const int prow = lane & 15;              // pred row
  const int pcol = w * 4 + hloc;           // pred hcol 0..31
  const float pb0 = pb[pcol * 4 + 0], pb1 = pb[pcol * 4 + 1];
  const float pb2 = pb[pcol * 4 + 2], pb3 = pb[pcol * 4 + 3];
  float cp = 0.f;
  __syncthreads();

  for (int s = 0; s < 128; s++) {
    if (s >= 1) {
      // ---- decode step s: h_{s-1} -> h_s (own 128 hcols) ----
      const u16* hr = &hbuf[(s - 1) & 1][0][0];
      f32x4 ai = {}, af = {}, ag = {}, ao = {};
#pragma unroll
      for (int kt = 0; kt < 8; kt++) {
        bfrag a = *(const bfrag*)(hr + m15 * 264 + kt * 32 + q * 8);
        ai = MFMA(a, WDi[kt], ai);
        af = MFMA(a, WDf[kt], af);
        ag = MFMA(a, WDg[kt], ag);
        ao = MFMA(a, WDo[kt], ao);
      }
      u16 hq[4];
#pragma unroll
      for (int r = 0; r < 4; r++) {
        float gi = ai[r] + rbv0, gf = af[r] + rbv1;
        float gg = ag[r] + rbv2, go = ao[r] + rbv3;
        float cn = ssig(gf) * cst[r] + ssig(gi) * stanh(gg);
        float hn = ssig(go) * stanh(cn);
        cst[r] = cn;
        hq[r] = f2b(hn);
      }
      // write own half: LDS + global exchange slot (shuffle-packed b32)
      u16* hw = &hbuf[s & 1][0][0];
      u16* hx = Hx + ((size_t)blk * 2 + (s & 1)) * 2048;
#pragma unroll
      for (int r = 0; r < 4; r++) {
        unsigned mine = hq[r];
        unsigned other = (unsigned)__shfl_xor((int)mine, 1);
        if (!(m15 & 1)) {
          unsigned pk = mine | (other << 16);
          *(unsigned*)(hw + (q * 4 + r) * 264 + half * 128 + (hcL & ~1)) = pk;
          *(unsigned*)(hx + (q * 4 + r) * 128 + (hcL & ~1)) = pk;
        }
      }
      __threadfence();       // per-thread: drain + L2 writeback (agent scope)
      __syncthreads();       // all threads' data at coherent point
      if (tid == 0)
        __hip_atomic_store(&flags[blk], s, __ATOMIC_RELEASE, __HIP_MEMORY_SCOPE_AGENT);
      if (tid < 64) {        // wave 0 spins for partner's h_s (bounded)
        int guard = 0;
        while (__hip_atomic_load(&flags[partner], __ATOMIC_ACQUIRE,
                                 __HIP_MEMORY_SCOPE_AGENT) < s &&
               guard < (1 << 24)) {
          __builtin_amdgcn_s_sleep(1);
          guard++;
        }
      }
      __syncthreads();
      // copy partner half into hbuf (16 rows x 128 cols, 8B/thread)
      {
        const u16* src = Hx + ((size_t)partner * 2 + (s & 1)) * 2048;
        int r = tid >> 5, c4 = (tid & 31) * 4;
        *(unsigned long long*)(&hbuf[s & 1][0][0] + r * 264 + (1 - half) * 128 + c4) =
            *(const unsigned long long*)(src + r * 128 + c4);
      }
      __syncthreads();       // hbuf[s&1] complete
    }
    // ---- predictor step s: x = h_s (full, in hbuf[s&1]) ----
    {
      const u16* xr = &hbuf[s & 1][0][0];
      f32x4 pacc = {};
#pragma unroll
      for (int kt = 0; kt < 8; kt++) {
        bfrag a = *(const bfrag*)(xr + m15 * 264 + kt * 32 + q * 8);
        pacc = MFMA(a, WP[kt], pacc);
      }
      {
        bfrag ah = *(const bfrag*)(&hp[s & 1][m15][q * 8]);
        pacc = MFMA(ah, WPH, pacc);
      }
      // per-wave transpose (in-order DS, no barrier): [tilecol][row]
      *(f32x4*)&gbuf[w][m15][q * 4] = pacc;
      float g0 = gbuf[w][hloc * 4 + 0][prow] + pb0;
      float g1 = gbuf[w][hloc * 4 + 1][prow] + pb1;
      float g2 = gbuf[w][hloc * 4 + 2][prow] + pb2;
      float g3 = gbuf[w][hloc * 4 + 3][prow] + pb3;
      float cn = ssig(g1) * cp + ssig(g0) * stanh(g2);
      float hn = ssig(g3) * stanh(cn);
      cp = cn;
      hp[(s + 1) & 1][prow][pcol] = f2b(hn);
      ys[prow][pcol] = hn;
      __syncthreads();
      if (tid < 16) {
        float m = ys[tid][0];
        for (int j = 1; j < 31; j++) m = fmaxf(m, ys[tid][j]);
        float ssum = 0.f;
        for (int j = 0; j < 31; j++) ssum += __expf(ys[tid][j] - m);
        smv[tid] = m; siv[tid] = 1.f / ssum;
      }
      __syncthreads();
      float v = (pcol < 31) ? __expf(hn - smv[prow]) * siv[prow] : ssig(hn);
      out[(size_t)(rowg + prow) * 4096 + s * 32 + pcol] = v;
    }
  }
}

// ---------------------------------------------------------------------------
extern "C" void kernel_launch(void* const* d_in, const int* in_sizes, int n_in,
                              void* d_out, int out_size, void* d_ws, size_t ws_size,
                              hipStream_t stream) {
  (void)in_sizes; (void)n_in; (void)out_size; (void)ws_size;
  const float* x    = (const float*)d_in[0];
  const float* W1   = (const float*)d_in[1];
  const float* b1   = (const float*)d_in[2];
  const float* W2   = (const float*)d_in[3];
  const float* b2   = (const float*)d_in[4];
  const float* W3   = (const float*)d_in[5];
  const float* b3   = (const float*)d_in[6];
  const float* Wh1  = (const float*)d_in[7];
  const float* bh1  = (const float*)d_in[8];
  const float* Wh2  = (const float*)d_in[9];
  const float* bh2  = (const float*)d_in[10];
  const float* Wc1  = (const float*)d_in[11];
  const float* bc1  = (const float*)d_in[12];
  const float* Wc2  = (const float*)d_in[13];
  const float* bc2  = (const float*)d_in[14];
  const float* Wx1  = (const float*)d_in[15];
  const float* bx1  = (const float*)d_in[16];
  const float* Wx2  = (const float*)d_in[17];
  const float* bx2  = (const float*)d_in[18];
  const float* rWih = (const float*)d_in[19];
  const float* rWhh = (const float*)d_in[20];
  const float* rbih = (const float*)d_in[21];
  const float* rbhh = (const float*)d_in[22];
  const float* pWih = (const float*)d_in[23];
  const float* pWhh = (const float*)d_in[24];
  const float* pbih = (const float*)d_in[25];
  const float* pbhh = (const float*)d_in[26];

  char* w = (char*)d_ws;
  auto alloc = [&](size_t bytes) -> char* {
    char* p = w;
    w += (bytes + 255) & ~(size_t)255;
    return p;
  };
  u16* Xbf  = (u16*)alloc(1024 * 128 * 2);
  u16* T1   = (u16*)alloc(1024 * 512 * 2);
  u16* T2   = (u16*)alloc(1024 * 512 * 2);
  u16* T3   = (u16*)alloc(1024 * 512 * 2);
  u16* TH   = (u16*)alloc(1024 * 512 * 2);
  u16* TC   = (u16*)alloc(1024 * 512 * 2);
  u16* TX   = (u16*)alloc(1024 * 512 * 2);
  u16* X0H  = (u16*)alloc(1024 * 512 * 2);  // cols 0..255 = x0, 256..511 = h
  float* CB = (float*)alloc(1024 * 256 * 4);
  u16* OUTS0= (u16*)alloc(1024 * 256 * 2);  // h_0 only
  u16* W1b  = (u16*)alloc(512 * 128 * 2);
  u16* W2b  = (u16*)alloc(512 * 512 * 2);
  u16* W3b  = (u16*)alloc(512 * 512 * 2);
  u16* Wh1b = (u16*)alloc(512 * 512 * 2);
  u16* Wc1b = (u16*)alloc(512 * 512 * 2);
  u16* Wx1b = (u16*)alloc(512 * 512 * 2);
  u16* Wh2b = (u16*)alloc(256 * 512 * 2);
  u16* Wc2b = (u16*)alloc(256 * 512 * 2);
  u16* Wx2b = (u16*)alloc(256 * 512 * 2);
  u16* WcR  = (u16*)alloc(1024 * 256 * 2);
  u16* WcatR= (u16*)alloc(1024 * 512 * 2);
  float* rbR = (float*)alloc(1024 * 4);
  u16* pWR  = (u16*)alloc(128 * 256 * 2);
  u16* pWhhR= (u16*)alloc(128 * 32 * 2);
  float* pbR = (float*)alloc(128 * 4);
  u16* Hx   = (u16*)alloc(128 * 2 * 2048 * 2);  // 1 MB exchange ping-pong
  int* flags= (int*)alloc(128 * 4);             // poison 0xAA.. < 1 => not-ready

  PrepArgs pa;
  pa.x = x; pa.W1 = W1; pa.W2 = W2; pa.W3 = W3; pa.Wh1 = Wh1; pa.Wc1 = Wc1; pa.Wx1 = Wx1;
  pa.Wh2 = Wh2; pa.Wc2 = Wc2; pa.Wx2 = Wx2;
  pa.rWih = rWih; pa.rWhh = rWhh; pa.rbih = rbih; pa.rbhh = rbhh;
  pa.pWih = pWih; pa.pWhh = pWhh; pa.pbih = pbih; pa.pbhh = pbhh;
  pa.Xbf = Xbf; pa.W1b = W1b; pa.W2b = W2b; pa.W3b = W3b; pa.Wh1b = Wh1b;
  pa.Wc1b = Wc1b; pa.Wx1b = Wx1b; pa.Wh2b = Wh2b; pa.Wc2b = Wc2b; pa.Wx2b = Wx2b;
  pa.WcR = WcR; pa.WcatR = WcatR; pa.pWR = pWR; pa.pWhhR = pWhhR;
  pa.rbR = rbR; pa.pbR = pbR;
  prep<<<dim3(32, 15), 256, 0, stream>>>(pa);

  // MLP + heads
  gemm_act<<<dim3(16, 8), 256, 0, stream>>>(Xbf, W1b, b1, T1, nullptr, 128, 512, 0, 1);
  gemm_act<<<dim3(16, 8), 256, 0, stream>>>(T1, W2b, b2, T2, nullptr, 512, 512, 0, 1);
  gemm_act<<<dim3(16, 8), 256, 0, stream>>>(T2, W3b, b3, T3, nullptr, 512, 512, 0, 1);
  gemm_act<<<dim3(16, 8), 256, 0, stream>>>(T3, Wh1b, bh1, TH, nullptr, 512, 512, 0, 1);
  gemm_act<<<dim3(16, 8), 256, 0, stream>>>(T3, Wc1b, bc1, TC, nullptr, 512, 512, 0, 1);
  gemm_act<<<dim3(16, 8), 256, 0, stream>>>(T3, Wx1b, bx1, TX, nullptr, 512, 512, 0, 1);
  gemm_act<<<dim3(16, 4), 256, 0, stream>>>(TH, Wh2b, bh2, X0H, nullptr, 512, 512, 256, 0); // h
  gemm_act<<<dim3(16, 4), 256, 0, stream>>>(TC, Wc2b, bc2, nullptr, CB, 512, 256, 0, 0);    // c (fp32)
  gemm_act<<<dim3(16, 4), 256, 0, stream>>>(TX, Wx2b, bx2, X0H, nullptr, 512, 512, 0, 0);   // x0

  // decode step 0 (K=512 concat), then fused decode(1..127)+predictor(0..127)
  decode_step<<<dim3(16, 8), 256, 0, stream>>>(X0H, WcatR, rbR, CB, OUTS0, 512);
  decode_pred<<<128, 512, 0, stream>>>(WcR, rbR, CB, OUTS0, pWR, pWhhR, pbR,
                                       Hx, flags, (float*)d_out);
}

// Round 6
// 1610.787 us; speedup vs baseline: 2.7411x; 2.7411x over previous
//
#include <hip/hip_runtime.h>

typedef unsigned short u16;
typedef __attribute__((ext_vector_type(8))) __bf16 bfrag;
typedef __attribute__((ext_vector_type(4))) float f32x4;

static __device__ __forceinline__ f32x4 MFMA(bfrag a, bfrag b, f32x4 c) {
  return __builtin_amdgcn_mfma_f32_16x16x32_bf16(a, b, c, 0, 0, 0);
}

// float -> bf16 (RNE)
static __device__ __forceinline__ u16 f2b(float f) {
  union { float f; unsigned u; } v; v.f = f;
  unsigned r = (v.u + 0x7fffu + ((v.u >> 16) & 1u)) >> 16;
  return (u16)r;
}
static __device__ __forceinline__ float ssig(float x) { return 1.f / (1.f + __expf(-x)); }
static __device__ __forceinline__ float stanh(float x) { return 1.f - 2.f / (__expf(2.f * x) + 1.f); }

// ---------------------------------------------------------------------------
// prep: bf16 casts + gate-retiled decode weights.
// Decode: MFMA col n = w*64 + gate*16 + m15 <-> source row gate*256 + w*16 + m15.
// Case 15: g-gate weights in lane-swizzled LDS-staging order:
//   WgS[((w*8+kt)*64+lane)*8+j] = Wc[gate=2, hcol=w*16+(lane&15)][k=kt*32+(lane>>4)*8+j]
// Predictor: n' = hcol*4 + gate (cases 12-14).
// ---------------------------------------------------------------------------
struct PrepArgs {
  const float *x, *W1, *W2, *W3, *Wh1, *Wc1, *Wx1, *Wh2, *Wc2, *Wx2;
  const float *rWih, *rWhh, *rbih, *rbhh, *pWih, *pWhh, *pbih, *pbhh;
  u16 *Xbf, *W1b, *W2b, *W3b, *Wh1b, *Wc1b, *Wx1b, *Wh2b, *Wc2b, *Wx2b;
  u16 *WcR, *WcatR, *pWR, *pWhhR, *WgS;
  float *rbR, *pbR;
};

__global__ __launch_bounds__(256) void prep(PrepArgs p) {
  const int tid0 = blockIdx.x * 256 + threadIdx.x;
  const int stride = gridDim.x * 256;
  switch (blockIdx.y) {
    case 0: for (int i = tid0; i < 131072; i += stride) p.Xbf[i] = f2b(p.x[i]); break;
    case 1: for (int i = tid0; i < 65536;  i += stride) p.W1b[i] = f2b(p.W1[i]); break;
    case 2: for (int i = tid0; i < 262144; i += stride) p.W2b[i] = f2b(p.W2[i]); break;
    case 3: for (int i = tid0; i < 262144; i += stride) p.W3b[i] = f2b(p.W3[i]); break;
    case 4: for (int i = tid0; i < 262144; i += stride) p.Wh1b[i] = f2b(p.Wh1[i]); break;
    case 5: for (int i = tid0; i < 262144; i += stride) p.Wc1b[i] = f2b(p.Wc1[i]); break;
    case 6: for (int i = tid0; i < 262144; i += stride) p.Wx1b[i] = f2b(p.Wx1[i]); break;
    case 7: for (int i = tid0; i < 131072; i += stride) p.Wh2b[i] = f2b(p.Wh2[i]); break;
    case 8: for (int i = tid0; i < 131072; i += stride) p.Wc2b[i] = f2b(p.Wc2[i]); break;
    case 9: for (int i = tid0; i < 131072; i += stride) p.Wx2b[i] = f2b(p.Wx2[i]); break;
    case 10: // decode weights: combined (steps>=1) and concat (step 0), gate-retiled
      for (int i = tid0; i < 262144; i += stride) {
        int n = i >> 8, k = i & 255;
        int srow = (((n >> 4) & 3) << 8) + ((n >> 6) << 4) + (n & 15);
        float a = p.rWih[srow * 256 + k], b = p.rWhh[srow * 256 + k];
        p.WcR[i] = f2b(a + b);
        p.WcatR[n * 512 + k] = f2b(a);
        p.WcatR[n * 512 + 256 + k] = f2b(b);
      }
      break;
    case 11:
      for (int i = tid0; i < 1024; i += stride) {
        int srow = (((i >> 4) & 3) << 8) + ((i >> 6) << 4) + (i & 15);
        p.rbR[i] = p.rbih[srow] + p.rbhh[srow];
      }
      break;
    case 12:
      for (int i = tid0; i < 32768; i += stride) {
        int n2 = i >> 8, k = i & 255;
        int srow = ((n2 & 3) << 5) + (n2 >> 2);
        p.pWR[i] = f2b(p.pWih[srow * 256 + k]);
      }
      break;
    case 13:
      for (int i = tid0; i < 4096; i += stride) {
        int n2 = i >> 5, k = i & 31;
        int srow = ((n2 & 3) << 5) + (n2 >> 2);
        p.pWhhR[i] = f2b(p.pWhh[srow * 32 + k]);
      }
      break;
    case 14:
      for (int i = tid0; i < 128; i += stride) {
        int srow = ((i & 3) << 5) + (i >> 2);
        p.pbR[i] = p.pbih[srow] + p.pbhh[srow];
      }
      break;
    case 15: // g-gate weights, lane-swizzled for conflict-free LDS staging
      for (int i = tid0; i < 65536; i += stride) {
        int j = i & 7, lane = (i >> 3) & 63, kt = (i >> 9) & 7, w = i >> 12;
        int srow = 512 + w * 16 + (lane & 15);           // gate g source row
        int k = kt * 32 + (lane >> 4) * 8 + j;
        p.WgS[i] = f2b(p.rWih[srow * 256 + k] + p.rWhh[srow * 256 + k]);
      }
      break;
  }
}

// ---------------------------------------------------------------------------
// gemm_act: Y[1024,N] = act(X[1024,K] @ W[N,K]^T + bias), bf16 in, fp32 acc.
// ---------------------------------------------------------------------------
__global__ __launch_bounds__(256) void gemm_act(
    const u16* __restrict__ X, const u16* __restrict__ W,
    const float* __restrict__ bias,
    u16* __restrict__ Yb, float* __restrict__ Yf,
    int K, int ldo, int coloff, int leaky) {
  const int rt = blockIdx.x, ct = blockIdx.y;
  const int lane = threadIdx.x & 63, wave = threadIdx.x >> 6;
  const int m15 = lane & 15, q = lane >> 4, kq = q * 8;
  const int row = rt * 64 + wave * 16 + m15;
  f32x4 acc[4] = {};
  const u16* xp = X + (size_t)row * K + kq;
  for (int k0 = 0; k0 < K; k0 += 32) {
    bfrag a = *(const bfrag*)(xp + k0);
#pragma unroll
    for (int nt = 0; nt < 4; nt++) {
      const u16* wp = W + (size_t)(ct * 64 + nt * 16 + m15) * K + k0 + kq;
      acc[nt] = MFMA(a, *(const bfrag*)wp, acc[nt]);
    }
  }
#pragma unroll
  for (int nt = 0; nt < 4; nt++) {
    int col = ct * 64 + nt * 16 + m15;
    float bv = bias[col];
#pragma unroll
    for (int r = 0; r < 4; r++) {
      int orow = rt * 64 + wave * 16 + q * 4 + r;
      float v = acc[nt][r] + bv;
      if (leaky) v = v >= 0.f ? v : 0.2f * v;
      if (Yb) Yb[(size_t)orow * ldo + coloff + col] = f2b(v);
      else    Yf[(size_t)orow * ldo + coloff + col] = v;
    }
  }
}

// ---------------------------------------------------------------------------
// decode_step: step 0 only (K=512 concat input), gate-retiled columns.
// ---------------------------------------------------------------------------
__global__ __launch_bounds__(256) void decode_step(
    const u16* __restrict__ A, const u16* __restrict__ W,
    const float* __restrict__ rb,
    float* __restrict__ C, u16* __restrict__ Hout, int K) {
  __shared__ float g[64][128];
  const int rt = blockIdx.x, cg = blockIdx.y;
  const int lane = threadIdx.x & 63, wave = threadIdx.x >> 6;
  const int m15 = lane & 15, q = lane >> 4, kq = q * 8;
  const int row = rt * 64 + wave * 16 + m15;
  f32x4 acc[8] = {};
  const u16* ap = A + (size_t)row * K + kq;
  for (int k0 = 0; k0 < K; k0 += 32) {
    bfrag a = *(const bfrag*)(ap + k0);
#pragma unroll
    for (int nt = 0; nt < 8; nt++) {
      const u16* wp = W + (size_t)(cg * 128 + nt * 16 + m15) * K + k0 + kq;
      acc[nt] = MFMA(a, *(const bfrag*)wp, acc[nt]);
    }
  }
#pragma unroll
  for (int nt = 0; nt < 8; nt++)
#pragma unroll
    for (int r = 0; r < 4; r++)
      g[wave * 16 + q * 4 + r][nt * 16 + m15] = acc[nt][r];
  __syncthreads();
  for (int t = threadIdx.x; t < 2048; t += 256) {
    int rl = t >> 5, hc = t & 31;
    int grow = rt * 64 + rl, gcol = cg * 32 + hc;
    int base = ((hc >> 4) << 6) + (hc & 15);
    float gi = g[rl][base +  0] + rb[cg * 128 + base +  0];
    float gf = g[rl][base + 16] + rb[cg * 128 + base + 16];
    float gg = g[rl][base + 32] + rb[cg * 128 + base + 32];
    float go = g[rl][base + 48] + rb[cg * 128 + base + 48];
    size_t ci = (size_t)grow * 256 + gcol;
    float c = C[ci];
    float cn = ssig(gf) * c + ssig(gi) * stanh(gg);
    float hn = ssig(go) * stanh(cn);
    C[ci] = cn;
    Hout[ci] = f2b(hn);
  }
}

// ---------------------------------------------------------------------------
// decode_pred v2: 64 blocks x 1024 thr (16 waves), block = 16 rows x ALL 256
// hcols -> zero inter-block sync (R5's 30us/step handshake eliminated).
// Wave w = gates i,f,g,o of hcols w*16..w*16+15, in-lane LSTM math.
// Weight placement per step (the round-3/4 bottleneck was 512 KB/step/CU
// streamed from L2 at ~27 B/cyc = 19.7K cyc/step):
//   i,f: 64 VGPRs/lane, pinned live via asm (un-rematerializable)
//   g:   128 KB staged once in LDS, lane-swizzled (conflict-free)
//   o + predictor: streamed from L2 (~192 KB/step/CU => ~7K cyc/step)
// Predictor fused: h_s consumed from LDS, softmax/sigmoid -> d_out.
// ---------------------------------------------------------------------------
__global__ __launch_bounds__(1024, 4) void decode_pred(
    const u16* __restrict__ W,      // WcR [1024][256] gate-retiled (i,f,o)
    const u16* __restrict__ Wg,     // WgS [65536] swizzled g-gate
    const float* __restrict__ rb,   // rbR [1024]
    const float* __restrict__ C0,   // CB  [1024][256] (c after step 0)
    const u16* __restrict__ H0,     // h_0 [1024][256]
    const u16* __restrict__ pW,     // pWR  [128][256]
    const u16* __restrict__ pWhh,   // pWhhR [128][32]
    const float* __restrict__ pb,   // pbR [128]
    float* __restrict__ out) {      // [1024][128][32]
  __shared__ u16 wgl[16][8][512];      // 128 KB g-gate weights
  __shared__ u16 hbuf[2][16][264];     // 16.9 KB
  __shared__ float gbuf[8][16][20];    // 10 KB pred transpose
  __shared__ u16 hp[2][16][40];        // 2.5 KB pred hidden
  __shared__ float ys[16][36];         // 2.25 KB
  __shared__ float smv[16], siv[16];
  const int tid = threadIdx.x;
  const int w = tid >> 6, lane = tid & 63;
  const int m15 = lane & 15, q = lane >> 4;
  const int rowg = blockIdx.x * 16;
  const int hc = w * 16 + m15;

  // stage g-gate weights (one-time, coalesced, layout == read order)
  for (int i = tid * 8; i < 65536; i += 8192)
    *(bfrag*)(&wgl[0][0][0] + i) = *(const bfrag*)(Wg + i);
  // h_0: 16 rows x 256 cols, 8 B/thread
  {
    int r = tid >> 6, c = (tid & 63) * 4;
    *(unsigned long long*)(&hbuf[0][r][c]) =
        *(const unsigned long long*)(H0 + (size_t)(rowg + r) * 256 + c);
  }
  for (int i = tid; i < 2 * 16 * 40; i += 1024) (&hp[0][0][0])[i] = 0;

  // per-lane decode state
  float cst[4];
#pragma unroll
  for (int r = 0; r < 4; r++)
    cst[r] = C0[(size_t)(rowg + q * 4 + r) * 256 + hc];
  const float rbv0 = rb[w * 64 +  0 + m15], rbv1 = rb[w * 64 + 16 + m15];
  const float rbv2 = rb[w * 64 + 32 + m15], rbv3 = rb[w * 64 + 48 + m15];

  const u16* wb = W + (size_t)(w * 64 + m15) * 256 + q * 8;
  bfrag WDi[8], WDf[8];
#pragma unroll
  for (int kt = 0; kt < 8; kt++) {
    WDi[kt] = *(const bfrag*)(wb + kt * 32);            // gate i
    WDf[kt] = *(const bfrag*)(wb + 4096 + kt * 32);     // gate f
  }
#pragma unroll
  for (int kt = 0; kt < 8; kt++) {
    asm volatile("" : "+v"(WDi[kt]));   // pin: cannot be rematerialized
    asm volatile("" : "+v"(WDf[kt]));
  }
  const u16* wo = wb + 12288;           // gate o, streamed

  // predictor constants (waves 0..7 active)
  const int hloc = lane >> 4, prow = lane & 15;
  const int pcol = w * 4 + hloc;
  const int pc = (w < 8) ? pcol : 0;
  const float pb0 = pb[pc * 4 + 0], pb1 = pb[pc * 4 + 1];
  const float pb2 = pb[pc * 4 + 2], pb3 = pb[pc * 4 + 3];
  float cp = 0.f;
  __syncthreads();

  for (int s = 0; s < 128; s++) {
    asm volatile("" ::: "memory");   // block LICM of per-step streamed loads
    if (s) {
      // ---- decode step s: h_{s-1} -> h_s ----
      const u16* hr = &hbuf[(s - 1) & 1][0][0];
      f32x4 ai = {}, af = {}, ag = {}, ao = {};
#pragma unroll
      for (int kt = 0; kt < 8; kt++) {
        bfrag a  = *(const bfrag*)(hr + m15 * 264 + kt * 32 + q * 8);
        bfrag bg = *(const bfrag*)(&wgl[w][kt][0] + lane * 8);
        bfrag bo = *(const bfrag*)(wo + kt * 32);
        ai = MFMA(a, WDi[kt], ai);
        af = MFMA(a, WDf[kt], af);
        ag = MFMA(a, bg, ag);
        ao = MFMA(a, bo, ao);
      }
      u16 hq[4];
#pragma unroll
      for (int r = 0; r < 4; r++) {
        float gi = ai[r] + rbv0, gf = af[r] + rbv1;
        float gg = ag[r] + rbv2, go = ao[r] + rbv3;
        float cn = ssig(gf) * cst[r] + ssig(gi) * stanh(gg);
        float hn = ssig(go) * stanh(cn);
        cst[r] = cn;
        hq[r] = f2b(hn);
      }
      u16* hw = &hbuf[s & 1][0][0];
#pragma unroll
      for (int r = 0; r < 4; r++) {
        unsigned mine = hq[r];
        unsigned other = (unsigned)__shfl_xor((int)mine, 1);
        if (!(m15 & 1))
          *(unsigned*)(hw + (q * 4 + r) * 264 + (hc & ~1)) = mine | (other << 16);
      }
      __syncthreads();
    }
    // ---- predictor step s (waves 0..7) ----
    float hn_p = 0.f;
    if (w < 8) {
      const u16* xr = &hbuf[s & 1][0][0];
      f32x4 pacc = {};
#pragma unroll
      for (int kt = 0; kt < 8; kt++) {
        bfrag a  = *(const bfrag*)(xr + m15 * 264 + kt * 32 + q * 8);
        bfrag bp = *(const bfrag*)(pW + (size_t)(w * 16 + m15) * 256 + kt * 32 + q * 8);
        pacc = MFMA(a, bp, pacc);
      }
      {
        bfrag ah = *(const bfrag*)(&hp[s & 1][m15][q * 8]);
        bfrag bh = *(const bfrag*)(pWhh + (size_t)(w * 16 + m15) * 32 + q * 8);
        pacc = MFMA(ah, bh, pacc);
      }
      *(f32x4*)&gbuf[w][m15][q * 4] = pacc;  // per-wave transpose, in-order DS
      float g0 = gbuf[w][hloc * 4 + 0][prow] + pb0;
      float g1 = gbuf[w][hloc * 4 + 1][prow] + pb1;
      float g2 = gbuf[w][hloc * 4 + 2][prow] + pb2;
      float g3 = gbuf[w][hloc * 4 + 3][prow] + pb3;
      float cn = ssig(g1) * cp + ssig(g0) * stanh(g2);
      hn_p = ssig(g3) * stanh(cn);
      cp = cn;
      hp[(s + 1) & 1][prow][pcol] = f2b(hn_p);
      ys[prow][pcol] = hn_p;
    }
    __syncthreads();
    if (tid < 16) {
      float m = ys[tid][0];
      for (int j = 1; j < 31; j++) m = fmaxf(m, ys[tid][j]);
      float ssum = 0.f;
      for (int j = 0; j < 31; j++) ssum += __expf(ys[tid][j] - m);
      smv[tid] = m; siv[tid] = 1.f / ssum;
    }
    __syncthreads();
    if (w < 8) {
      float v = (pcol < 31) ? __expf(hn_p - smv[prow]) * siv[prow] : ssig(hn_p);
      out[(size_t)(rowg + prow) * 4096 + s * 32 + pcol] = v;
    }
  }
}

// ---------------------------------------------------------------------------
extern "C" void kernel_launch(void* const* d_in, const int* in_sizes, int n_in,
                              void* d_out, int out_size, void* d_ws, size_t ws_size,
                              hipStream_t stream) {
  (void)in_sizes; (void)n_in; (void)out_size; (void)ws_size;
  const float* x    = (const float*)d_in[0];
  const float* W1   = (const float*)d_in[1];
  const float* b1   = (const float*)d_in[2];
  const float* W2   = (const float*)d_in[3];
  const float* b2   = (const float*)d_in[4];
  const float* W3   = (const float*)d_in[5];
  const float* b3   = (const float*)d_in[6];
  const float* Wh1  = (const float*)d_in[7];
  const float* bh1  = (const float*)d_in[8];
  const float* Wh2  = (const float*)d_in[9];
  const float* bh2  = (const float*)d_in[10];
  const float* Wc1  = (const float*)d_in[11];
  const float* bc1  = (const float*)d_in[12];
  const float* Wc2  = (const float*)d_in[13];
  const float* bc2  = (const float*)d_in[14];
  const float* Wx1  = (const float*)d_in[15];
  const float* bx1  = (const float*)d_in[16];
  const float* Wx2  = (const float*)d_in[17];
  const float* bx2  = (const float*)d_in[18];
  const float* rWih = (const float*)d_in[19];
  const float* rWhh = (const float*)d_in[20];
  const float* rbih = (const float*)d_in[21];
  const float* rbhh = (const float*)d_in[22];
  const float* pWih = (const float*)d_in[23];
  const float* pWhh = (const float*)d_in[24];
  const float* pbih = (const float*)d_in[25];
  const float* pbhh = (const float*)d_in[26];

  char* w = (char*)d_ws;
  auto alloc = [&](size_t bytes) -> char* {
    char* p = w;
    w += (bytes + 255) & ~(size_t)255;
    return p;
  };
  u16* Xbf  = (u16*)alloc(1024 * 128 * 2);
  u16* T1   = (u16*)alloc(1024 * 512 * 2);
  u16* T2   = (u16*)alloc(1024 * 512 * 2);
  u16* T3   = (u16*)alloc(1024 * 512 * 2);
  u16* TH   = (u16*)alloc(1024 * 512 * 2);
  u16* TC   = (u16*)alloc(1024 * 512 * 2);
  u16* TX   = (u16*)alloc(1024 * 512 * 2);
  u16* X0H  = (u16*)alloc(1024 * 512 * 2);  // cols 0..255 = x0, 256..511 = h
  float* CB = (float*)alloc(1024 * 256 * 4);
  u16* OUTS0= (u16*)alloc(1024 * 256 * 2);  // h_0 only
  u16* W1b  = (u16*)alloc(512 * 128 * 2);
  u16* W2b  = (u16*)alloc(512 * 512 * 2);
  u16* W3b  = (u16*)alloc(512 * 512 * 2);
  u16* Wh1b = (u16*)alloc(512 * 512 * 2);
  u16* Wc1b = (u16*)alloc(512 * 512 * 2);
  u16* Wx1b = (u16*)alloc(512 * 512 * 2);
  u16* Wh2b = (u16*)alloc(256 * 512 * 2);
  u16* Wc2b = (u16*)alloc(256 * 512 * 2);
  u16* Wx2b = (u16*)alloc(256 * 512 * 2);
  u16* WcR  = (u16*)alloc(1024 * 256 * 2);
  u16* WcatR= (u16*)alloc(1024 * 512 * 2);
  u16* WgS  = (u16*)alloc(65536 * 2);
  float* rbR = (float*)alloc(1024 * 4);
  u16* pWR  = (u16*)alloc(128 * 256 * 2);
  u16* pWhhR= (u16*)alloc(128 * 32 * 2);
  float* pbR = (float*)alloc(128 * 4);

  PrepArgs pa;
  pa.x = x; pa.W1 = W1; pa.W2 = W2; pa.W3 = W3; pa.Wh1 = Wh1; pa.Wc1 = Wc1; pa.Wx1 = Wx1;
  pa.Wh2 = Wh2; pa.Wc2 = Wc2; pa.Wx2 = Wx2;
  pa.rWih = rWih; pa.rWhh = rWhh; pa.rbih = rbih; pa.rbhh = rbhh;
  pa.pWih = pWih; pa.pWhh = pWhh; pa.pbih = pbih; pa.pbhh = pbhh;
  pa.Xbf = Xbf; pa.W1b = W1b; pa.W2b = W2b; pa.W3b = W3b; pa.Wh1b = Wh1b;
  pa.Wc1b = Wc1b; pa.Wx1b = Wx1b; pa.Wh2b = Wh2b; pa.Wc2b = Wc2b; pa.Wx2b = Wx2b;
  pa.WcR = WcR; pa.WcatR = WcatR; pa.pWR = pWR; pa.pWhhR = pWhhR; pa.WgS = WgS;
  pa.rbR = rbR; pa.pbR = pbR;
  prep<<<dim3(32, 16), 256, 0, stream>>>(pa);

  // MLP + heads
  gemm_act<<<dim3(16, 8), 256, 0, stream>>>(Xbf, W1b, b1, T1, nullptr, 128, 512, 0, 1);
  gemm_act<<<dim3(16, 8), 256, 0, stream>>>(T1, W2b, b2, T2, nullptr, 512, 512, 0, 1);
  gemm_act<<<dim3(16, 8), 256, 0, stream>>>(T2, W3b, b3, T3, nullptr, 512, 512, 0, 1);
  gemm_act<<<dim3(16, 8), 256, 0, stream>>>(T3, Wh1b, bh1, TH, nullptr, 512, 512, 0, 1);
  gemm_act<<<dim3(16, 8), 256, 0, stream>>>(T3, Wc1b, bc1, TC, nullptr, 512, 512, 0, 1);
  gemm_act<<<dim3(16, 8), 256, 0, stream>>>(T3, Wx1b, bx1, TX, nullptr, 512, 512, 0, 1);
  gemm_act<<<dim3(16, 4), 256, 0, stream>>>(TH, Wh2b, bh2, X0H, nullptr, 512, 512, 256, 0); // h
  gemm_act<<<dim3(16, 4), 256, 0, stream>>>(TC, Wc2b, bc2, nullptr, CB, 512, 256, 0, 0);    // c (fp32)
  gemm_act<<<dim3(16, 4), 256, 0, stream>>>(TX, Wx2b, bx2, X0H, nullptr, 512, 512, 0, 0);   // x0

  // decode step 0 (K=512 concat), then fused decode(1..127)+predictor(0..127)
  decode_step<<<dim3(16, 8), 256, 0, stream>>>(X0H, WcatR, rbR, CB, OUTS0, 512);
  decode_pred<<<64, 1024, 0, stream>>>(WcR, WgS, rbR, CB, OUTS0, pWR, pWhhR, pbR,
                                       (float*)d_out);
}

// Round 8
// 1476.563 us; speedup vs baseline: 2.9903x; 1.0909x over previous
//
#include <hip/hip_runtime.h>

typedef unsigned short u16;
typedef __attribute__((ext_vector_type(8))) __bf16 bfrag;
typedef __attribute__((ext_vector_type(4))) float f32x4;

static __device__ __forceinline__ f32x4 MFMA(bfrag a, bfrag b, f32x4 c) {
  return __builtin_amdgcn_mfma_f32_16x16x32_bf16(a, b, c, 0, 0, 0);
}

// float -> bf16 (RNE)
static __device__ __forceinline__ u16 f2b(float f) {
  union { float f; unsigned u; } v; v.f = f;
  unsigned r = (v.u + 0x7fffu + ((v.u >> 16) & 1u)) >> 16;
  return (u16)r;
}
static __device__ __forceinline__ float ssig(float x) { return 1.f / (1.f + __expf(-x)); }
static __device__ __forceinline__ float stanh(float x) { return 1.f - 2.f / (__expf(2.f * x) + 1.f); }

// ---------------------------------------------------------------------------
// prep: bf16 casts + gate-retiled decode weights.
// Decode: MFMA col n = w*64 + gate*16 + m15 <-> source row gate*256 + w*16 + m15.
// Case 15: g-gate weights in lane-swizzled LDS-staging order:
//   WgS[((w*8+kt)*64+lane)*8+j] = Wc[gate=2, hcol=w*16+(lane&15)][k=kt*32+(lane>>4)*8+j]
// Predictor: n' = hcol*4 + gate (cases 12-14).
// ---------------------------------------------------------------------------
struct PrepArgs {
  const float *x, *W1, *W2, *W3, *Wh1, *Wc1, *Wx1, *Wh2, *Wc2, *Wx2;
  const float *rWih, *rWhh, *rbih, *rbhh, *pWih, *pWhh, *pbih, *pbhh;
  u16 *Xbf, *W1b, *W2b, *W3b, *Wh1b, *Wc1b, *Wx1b, *Wh2b, *Wc2b, *Wx2b;
  u16 *WcR, *WcatR, *pWR, *pWhhR, *WgS;
  float *rbR, *pbR;
};

__global__ __launch_bounds__(256) void prep(PrepArgs p) {
  const int tid0 = blockIdx.x * 256 + threadIdx.x;
  const int stride = gridDim.x * 256;
  switch (blockIdx.y) {
    case 0: for (int i = tid0; i < 131072; i += stride) p.Xbf[i] = f2b(p.x[i]); break;
    case 1: for (int i = tid0; i < 65536;  i += stride) p.W1b[i] = f2b(p.W1[i]); break;
    case 2: for (int i = tid0; i < 262144; i += stride) p.W2b[i] = f2b(p.W2[i]); break;
    case 3: for (int i = tid0; i < 262144; i += stride) p.W3b[i] = f2b(p.W3[i]); break;
    case 4: for (int i = tid0; i < 262144; i += stride) p.Wh1b[i] = f2b(p.Wh1[i]); break;
    case 5: for (int i = tid0; i < 262144; i += stride) p.Wc1b[i] = f2b(p.Wc1[i]); break;
    case 6: for (int i = tid0; i < 262144; i += stride) p.Wx1b[i] = f2b(p.Wx1[i]); break;
    case 7: for (int i = tid0; i < 131072; i += stride) p.Wh2b[i] = f2b(p.Wh2[i]); break;
    case 8: for (int i = tid0; i < 131072; i += stride) p.Wc2b[i] = f2b(p.Wc2[i]); break;
    case 9: for (int i = tid0; i < 131072; i += stride) p.Wx2b[i] = f2b(p.Wx2[i]); break;
    case 10: // decode weights: combined (steps>=1) and concat (step 0), gate-retiled
      for (int i = tid0; i < 262144; i += stride) {
        int n = i >> 8, k = i & 255;
        int srow = (((n >> 4) & 3) << 8) + ((n >> 6) << 4) + (n & 15);
        float a = p.rWih[srow * 256 + k], b = p.rWhh[srow * 256 + k];
        p.WcR[i] = f2b(a + b);
        p.WcatR[n * 512 + k] = f2b(a);
        p.WcatR[n * 512 + 256 + k] = f2b(b);
      }
      break;
    case 11:
      for (int i = tid0; i < 1024; i += stride) {
        int srow = (((i >> 4) & 3) << 8) + ((i >> 6) << 4) + (i & 15);
        p.rbR[i] = p.rbih[srow] + p.rbhh[srow];
      }
      break;
    case 12:
      for (int i = tid0; i < 32768; i += stride) {
        int n2 = i >> 8, k = i & 255;
        int srow = ((n2 & 3) << 5) + (n2 >> 2);
        p.pWR[i] = f2b(p.pWih[srow * 256 + k]);
      }
      break;
    case 13:
      for (int i = tid0; i < 4096; i += stride) {
        int n2 = i >> 5, k = i & 31;
        int srow = ((n2 & 3) << 5) + (n2 >> 2);
        p.pWhhR[i] = f2b(p.pWhh[srow * 32 + k]);
      }
      break;
    case 14:
      for (int i = tid0; i < 128; i += stride) {
        int srow = ((i & 3) << 5) + (i >> 2);
        p.pbR[i] = p.pbih[srow] + p.pbhh[srow];
      }
      break;
    case 15: // g-gate weights, lane-swizzled for conflict-free LDS staging
      for (int i = tid0; i < 65536; i += stride) {
        int j = i & 7, lane = (i >> 3) & 63, kt = (i >> 9) & 7, w = i >> 12;
        int srow = 512 + w * 16 + (lane & 15);           // gate g source row
        int k = kt * 32 + (lane >> 4) * 8 + j;
        p.WgS[i] = f2b(p.rWih[srow * 256 + k] + p.rWhh[srow * 256 + k]);
      }
      break;
  }
}

// ---------------------------------------------------------------------------
// gemm_act: Y[1024,N] = act(X[1024,K] @ W[N,K]^T + bias), bf16 in, fp32 acc.
// ---------------------------------------------------------------------------
__global__ __launch_bounds__(256) void gemm_act(
    const u16* __restrict__ X, const u16* __restrict__ W,
    const float* __restrict__ bias,
    u16* __restrict__ Yb, float* __restrict__ Yf,
    int K, int ldo, int coloff, int leaky) {
  const int rt = blockIdx.x, ct = blockIdx.y;
  const int lane = threadIdx.x & 63, wave = threadIdx.x >> 6;
  const int m15 = lane & 15, q = lane >> 4, kq = q * 8;
  const int row = rt * 64 + wave * 16 + m15;
  f32x4 acc[4] = {};
  const u16* xp = X + (size_t)row * K + kq;
  for (int k0 = 0; k0 < K; k0 += 32) {
    bfrag a = *(const bfrag*)(xp + k0);
#pragma unroll
    for (int nt = 0; nt < 4; nt++) {
      const u16* wp = W + (size_t)(ct * 64 + nt * 16 + m15) * K + k0 + kq;
      acc[nt] = MFMA(a, *(const bfrag*)wp, acc[nt]);
    }
  }
#pragma unroll
  for (int nt = 0; nt < 4; nt++) {
    int col = ct * 64 + nt * 16 + m15;
    float bv = bias[col];
#pragma unroll
    for (int r = 0; r < 4; r++) {
      int orow = rt * 64 + wave * 16 + q * 4 + r;
      float v = acc[nt][r] + bv;
      if (leaky) v = v >= 0.f ? v : 0.2f * v;
      if (Yb) Yb[(size_t)orow * ldo + coloff + col] = f2b(v);
      else    Yf[(size_t)orow * ldo + coloff + col] = v;
    }
  }
}

// ---------------------------------------------------------------------------
// decode_step: step 0 only (K=512 concat input), gate-retiled columns.
// ---------------------------------------------------------------------------
__global__ __launch_bounds__(256) void decode_step(
    const u16* __restrict__ A, const u16* __restrict__ W,
    const float* __restrict__ rb,
    float* __restrict__ C, u16* __restrict__ Hout, int K) {
  __shared__ float g[64][128];
  const int rt = blockIdx.x, cg = blockIdx.y;
  const int lane = threadIdx.x & 63, wave = threadIdx.x >> 6;
  const int m15 = lane & 15, q = lane >> 4, kq = q * 8;
  const int row = rt * 64 + wave * 16 + m15;
  f32x4 acc[8] = {};
  const u16* ap = A + (size_t)row * K + kq;
  for (int k0 = 0; k0 < K; k0 += 32) {
    bfrag a = *(const bfrag*)(ap + k0);
#pragma unroll
    for (int nt = 0; nt < 8; nt++) {
      const u16* wp = W + (size_t)(cg * 128 + nt * 16 + m15) * K + k0 + kq;
      acc[nt] = MFMA(a, *(const bfrag*)wp, acc[nt]);
    }
  }
#pragma unroll
  for (int nt = 0; nt < 8; nt++)
#pragma unroll
    for (int r = 0; r < 4; r++)
      g[wave * 16 + q * 4 + r][nt * 16 + m15] = acc[nt][r];
  __syncthreads();
  for (int t = threadIdx.x; t < 2048; t += 256) {
    int rl = t >> 5, hc = t & 31;
    int grow = rt * 64 + rl, gcol = cg * 32 + hc;
    int base = ((hc >> 4) << 6) + (hc & 15);
    float gi = g[rl][base +  0] + rb[cg * 128 + base +  0];
    float gf = g[rl][base + 16] + rb[cg * 128 + base + 16];
    float gg = g[rl][base + 32] + rb[cg * 128 + base + 32];
    float go = g[rl][base + 48] + rb[cg * 128 + base + 48];
    size_t ci = (size_t)grow * 256 + gcol;
    float c = C[ci];
    float cn = ssig(gf) * c + ssig(gi) * stanh(gg);
    float hn = ssig(go) * stanh(cn);
    C[ci] = cn;
    Hout[ci] = f2b(hn);
  }
}

// ---------------------------------------------------------------------------
// decode_pred v3: 64 blocks x 1024 thr (16 waves), block = 16 rows x ALL 256
// hcols, zero inter-block sync. Wave w = gates i,f,g,o of hcols w*16..+15.
// Weight placement (R4/R6 lesson: per-CU L2 stream runs ~23-26 B/cyc, so
// every streamed KB costs ~40 cyc/step):
//   i,f: 64 VGPRs/lane, pinned with LOOP-CARRIED asm (R6's outside-loop pin
//        was rematerialized away -> VGPR_Count=64, everything streamed)
//   g:   128 KB staged once in LDS, lane-swizzled (conflict-free)
//   o + predictor: streamed (~192 KB/step/CU ~= 7.7K cyc/step), pointers
//        made loop-opaque via "+v" pins (per-lane pointers CANNOT take "+s":
//        R7's SGPR constraint on a lane-divergent pointer broke the backend).
// Predictor fused: h_s consumed from LDS, softmax/sigmoid -> d_out.
// ---------------------------------------------------------------------------
__global__ __launch_bounds__(1024, 4) void decode_pred(
    const u16* __restrict__ W,      // WcR [1024][256] gate-retiled (i,f,o)
    const u16* __restrict__ Wg,     // WgS [65536] swizzled g-gate
    const float* __restrict__ rb,   // rbR [1024]
    const float* __restrict__ C0,   // CB  [1024][256] (c after step 0)
    const u16* __restrict__ H0,     // h_0 [1024][256]
    const u16* __restrict__ pW,     // pWR  [128][256]
    const u16* __restrict__ pWhh,   // pWhhR [128][32]
    const float* __restrict__ pb,   // pbR [128]
    float* __restrict__ out) {      // [1024][128][32]
  __shared__ u16 wgl[16][8][512];      // 128 KB g-gate weights
  __shared__ u16 hbuf[2][16][264];     // 16.9 KB
  __shared__ float gbuf[8][16][20];    // 10 KB pred transpose
  __shared__ u16 hp[2][16][40];        // 2.5 KB pred hidden
  __shared__ float ys[16][36];         // 2.25 KB
  __shared__ float smv[16], siv[16];
  const int tid = threadIdx.x;
  const int w = tid >> 6, lane = tid & 63;
  const int m15 = lane & 15, q = lane >> 4;
  const int rowg = blockIdx.x * 16;
  const int hc = w * 16 + m15;

  // stage g-gate weights (one-time, coalesced, layout == read order)
  for (int i = tid * 8; i < 65536; i += 8192)
    *(bfrag*)(&wgl[0][0][0] + i) = *(const bfrag*)(Wg + i);
  // h_0: 16 rows x 256 cols, 8 B/thread
  {
    int r = tid >> 6, c = (tid & 63) * 4;
    *(unsigned long long*)(&hbuf[0][r][c]) =
        *(const unsigned long long*)(H0 + (size_t)(rowg + r) * 256 + c);
  }
  for (int i = tid; i < 2 * 16 * 40; i += 1024) (&hp[0][0][0])[i] = 0;

  // per-lane decode state
  float cst[4];
#pragma unroll
  for (int r = 0; r < 4; r++)
    cst[r] = C0[(size_t)(rowg + q * 4 + r) * 256 + hc];
  const float rbv0 = rb[w * 64 +  0 + m15], rbv1 = rb[w * 64 + 16 + m15];
  const float rbv2 = rb[w * 64 + 32 + m15], rbv3 = rb[w * 64 + 48 + m15];

  const u16* wb = W + (size_t)(w * 64 + m15) * 256 + q * 8;
  bfrag WDi[8], WDf[8];
#pragma unroll
  for (int kt = 0; kt < 8; kt++) {
    WDi[kt] = *(const bfrag*)(wb + kt * 32);            // gate i
    WDf[kt] = *(const bfrag*)(wb + 4096 + kt * 32);     // gate f
  }
  const u16* wo = wb + 12288;           // gate o, streamed
  const u16* pWl = pW + (size_t)(w * 16 + m15) * 256 + q * 8;        // streamed
  const u16* pWhl = pWhh + (size_t)(w * 16 + m15) * 32 + q * 8;      // streamed

  // predictor constants (waves 0..7 active)
  const int hloc = lane >> 4, prow = lane & 15;
  const int pcol = w * 4 + hloc;
  const int pc = (w < 8) ? pcol : 0;
  const float pb0 = pb[pc * 4 + 0], pb1 = pb[pc * 4 + 1];
  const float pb2 = pb[pc * 4 + 2], pb3 = pb[pc * 4 + 3];
  float cp = 0.f;
  __syncthreads();

  for (int s = 0; s < 128; s++) {
    if (s) {
      // streamed pointer opaque per iteration ("+v": lane-divergent pointer
      // lives in a VGPR pair; "+s" is illegal here)
      asm volatile("" : "+v"(wo));
      // ---- decode step s: h_{s-1} -> h_s ----
      const u16* hr = &hbuf[(s - 1) & 1][0][0];
      f32x4 ai = {}, af = {}, ag = {}, ao = {};
#pragma unroll
      for (int kt = 0; kt < 8; kt++) {
        // LOOP-CARRIED pin: this iteration's asm output feeds the next
        // iteration's input -> values must stay in registers for the whole
        // loop (remat from memory would be unsound: asm is opaque).
        asm volatile("" : "+v"(WDi[kt]), "+v"(WDf[kt]));
        bfrag a  = *(const bfrag*)(hr + m15 * 264 + kt * 32 + q * 8);
        bfrag bg = *(const bfrag*)(&wgl[w][kt][0] + lane * 8);
        bfrag bo = *(const bfrag*)(wo + kt * 32);
        ai = MFMA(a, WDi[kt], ai);
        af = MFMA(a, WDf[kt], af);
        ag = MFMA(a, bg, ag);
        ao = MFMA(a, bo, ao);
      }
      u16 hq[4];
#pragma unroll
      for (int r = 0; r < 4; r++) {
        float gi = ai[r] + rbv0, gf = af[r] + rbv1;
        float gg = ag[r] + rbv2, go = ao[r] + rbv3;
        float cn = ssig(gf) * cst[r] + ssig(gi) * stanh(gg);
        float hn = ssig(go) * stanh(cn);
        cst[r] = cn;
        hq[r] = f2b(hn);
      }
      u16* hw = &hbuf[s & 1][0][0];
#pragma unroll
      for (int r = 0; r < 4; r++) {
        unsigned mine = hq[r];
        unsigned other = (unsigned)__shfl_xor((int)mine, 1);
        if (!(m15 & 1))
          *(unsigned*)(hw + (q * 4 + r) * 264 + (hc & ~1)) = mine | (other << 16);
      }
      __syncthreads();
    }
    // ---- predictor step s (waves 0..7) ----
    float hn_p = 0.f;
    if (w < 8) {
      asm volatile("" : "+v"(pWl), "+v"(pWhl));  // keep pred weights streamed
      const u16* xr = &hbuf[s & 1][0][0];
      f32x4 pacc = {};
#pragma unroll
      for (int kt = 0; kt < 8; kt++) {
        bfrag a  = *(const bfrag*)(xr + m15 * 264 + kt * 32 + q * 8);
        bfrag bp = *(const bfrag*)(pWl + kt * 32);
        pacc = MFMA(a, bp, pacc);
      }
      {
        bfrag ah = *(const bfrag*)(&hp[s & 1][m15][q * 8]);
        bfrag bh = *(const bfrag*)pWhl;
        pacc = MFMA(ah, bh, pacc);
      }
      *(f32x4*)&gbuf[w][m15][q * 4] = pacc;  // per-wave transpose, in-order DS
      float g0 = gbuf[w][hloc * 4 + 0][prow] + pb0;
      float g1 = gbuf[w][hloc * 4 + 1][prow] + pb1;
      float g2 = gbuf[w][hloc * 4 + 2][prow] + pb2;
      float g3 = gbuf[w][hloc * 4 + 3][prow] + pb3;
      float cn = ssig(g1) * cp + ssig(g0) * stanh(g2);
      hn_p = ssig(g3) * stanh(cn);
      cp = cn;
      hp[(s + 1) & 1][prow][pcol] = f2b(hn_p);
      ys[prow][pcol] = hn_p;
    }
    __syncthreads();
    if (tid < 16) {
      float m = ys[tid][0];
      for (int j = 1; j < 31; j++) m = fmaxf(m, ys[tid][j]);
      float ssum = 0.f;
      for (int j = 0; j < 31; j++) ssum += __expf(ys[tid][j] - m);
      smv[tid] = m; siv[tid] = 1.f / ssum;
    }
    __syncthreads();
    if (w < 8) {
      float v = (pcol < 31) ? __expf(hn_p - smv[prow]) * siv[prow] : ssig(hn_p);
      out[(size_t)(rowg + prow) * 4096 + s * 32 + pcol] = v;
    }
  }
}

// ---------------------------------------------------------------------------
extern "C" void kernel_launch(void* const* d_in, const int* in_sizes, int n_in,
                              void* d_out, int out_size, void* d_ws, size_t ws_size,
                              hipStream_t stream) {
  (void)in_sizes; (void)n_in; (void)out_size; (void)ws_size;
  const float* x    = (const float*)d_in[0];
  const float* W1   = (const float*)d_in[1];
  const float* b1   = (const float*)d_in[2];
  const float* W2   = (const float*)d_in[3];
  const float* b2   = (const float*)d_in[4];
  const float* W3   = (const float*)d_in[5];
  const float* b3   = (const float*)d_in[6];
  const float* Wh1  = (const float*)d_in[7];
  const float* bh1  = (const float*)d_in[8];
  const float* Wh2  = (const float*)d_in[9];
  const float* bh2  = (const float*)d_in[10];
  const float* Wc1  = (const float*)d_in[11];
  const float* bc1  = (const float*)d_in[12];
  const float* Wc2  = (const float*)d_in[13];
  const float* bc2  = (const float*)d_in[14];
  const float* Wx1  = (const float*)d_in[15];
  const float* bx1  = (const float*)d_in[16];
  const float* Wx2  = (const float*)d_in[17];
  const float* bx2  = (const float*)d_in[18];
  const float* rWih = (const float*)d_in[19];
  const float* rWhh = (const float*)d_in[20];
  const float* rbih = (const float*)d_in[21];
  const float* rbhh = (const float*)d_in[22];
  const float* pWih = (const float*)d_in[23];
  const float* pWhh = (const float*)d_in[24];
  const float* pbih = (const float*)d_in[25];
  const float* pbhh = (const float*)d_in[26];

  char* w = (char*)d_ws;
  auto alloc = [&](size_t bytes) -> char* {
    char* p = w;
    w += (bytes + 255) & ~(size_t)255;
    return p;
  };
  u16* Xbf  = (u16*)alloc(1024 * 128 * 2);
  u16* T1   = (u16*)alloc(1024 * 512 * 2);
  u16* T2   = (u16*)alloc(1024 * 512 * 2);
  u16* T3   = (u16*)alloc(1024 * 512 * 2);
  u16* TH   = (u16*)alloc(1024 * 512 * 2);
  u16* TC   = (u16*)alloc(1024 * 512 * 2);
  u16* TX   = (u16*)alloc(1024 * 512 * 2);
  u16* X0H  = (u16*)alloc(1024 * 512 * 2);  // cols 0..255 = x0, 256..511 = h
  float* CB = (float*)alloc(1024 * 256 * 4);
  u16* OUTS0= (u16*)alloc(1024 * 256 * 2);  // h_0 only
  u16* W1b  = (u16*)alloc(512 * 128 * 2);
  u16* W2b  = (u16*)alloc(512 * 512 * 2);
  u16* W3b  = (u16*)alloc(512 * 512 * 2);
  u16* Wh1b = (u16*)alloc(512 * 512 * 2);
  u16* Wc1b = (u16*)alloc(512 * 512 * 2);
  u16* Wx1b = (u16*)alloc(512 * 512 * 2);
  u16* Wh2b = (u16*)alloc(256 * 512 * 2);
  u16* Wc2b = (u16*)alloc(256 * 512 * 2);
  u16* Wx2b = (u16*)alloc(256 * 512 * 2);
  u16* WcR  = (u16*)alloc(1024 * 256 * 2);
  u16* WcatR= (u16*)alloc(1024 * 512 * 2);
  u16* WgS  = (u16*)alloc(65536 * 2);
  float* rbR = (float*)alloc(1024 * 4);
  u16* pWR  = (u16*)alloc(128 * 256 * 2);
  u16* pWhhR= (u16*)alloc(128 * 32 * 2);
  float* pbR = (float*)alloc(128 * 4);

  PrepArgs pa;
  pa.x = x; pa.W1 = W1; pa.W2 = W2; pa.W3 = W3; pa.Wh1 = Wh1; pa.Wc1 = Wc1; pa.Wx1 = Wx1;
  pa.Wh2 = Wh2; pa.Wc2 = Wc2; pa.Wx2 = Wx2;
  pa.rWih = rWih; pa.rWhh = rWhh; pa.rbih = rbih; pa.rbhh = rbhh;
  pa.pWih = pWih; pa.pWhh = pWhh; pa.pbih = pbih; pa.pbhh = pbhh;
  pa.Xbf = Xbf; pa.W1b = W1b; pa.W2b = W2b; pa.W3b = W3b; pa.Wh1b = Wh1b;
  pa.Wc1b = Wc1b; pa.Wx1b = Wx1b; pa.Wh2b = Wh2b; pa.Wc2b = Wc2b; pa.Wx2b = Wx2b;
  pa.WcR = WcR; pa.WcatR = WcatR; pa.pWR = pWR; pa.pWhhR = pWhhR; pa.WgS = WgS;
  pa.rbR = rbR; pa.pbR = pbR;
  prep<<<dim3(32, 16), 256, 0, stream>>>(pa);

  // MLP + heads
  gemm_act<<<dim3(16, 8), 256, 0, stream>>>(Xbf, W1b, b1, T1, nullptr, 128, 512, 0, 1);
  gemm_act<<<dim3(16, 8), 256, 0, stream>>>(T1, W2b, b2, T2, nullptr, 512, 512, 0, 1);
  gemm_act<<<dim3(16, 8), 256, 0, stream>>>(T2, W3b, b3, T3, nullptr, 512, 512, 0, 1);
  gemm_act<<<dim3(16, 8), 256, 0, stream>>>(T3, Wh1b, bh1, TH, nullptr, 512, 512, 0, 1);
  gemm_act<<<dim3(16, 8), 256, 0, stream>>>(T3, Wc1b, bc1, TC, nullptr, 512, 512, 0, 1);
  gemm_act<<<dim3(16, 8), 256, 0, stream>>>(T3, Wx1b, bx1, TX, nullptr, 512, 512, 0, 1);
  gemm_act<<<dim3(16, 4), 256, 0, stream>>>(TH, Wh2b, bh2, X0H, nullptr, 512, 512, 256, 0); // h
  gemm_act<<<dim3(16, 4), 256, 0, stream>>>(TC, Wc2b, bc2, nullptr, CB, 512, 256, 0, 0);    // c (fp32)
  gemm_act<<<dim3(16, 4), 256, 0, stream>>>(TX, Wx2b, bx2, X0H, nullptr, 512, 512, 0, 0);   // x0

  // decode step 0 (K=512 concat), then fused decode(1..127)+predictor(0..127)
  decode_step<<<dim3(16, 8), 256, 0, stream>>>(X0H, WcatR, rbR, CB, OUTS0, 512);
  decode_pred<<<64, 1024, 0, stream>>>(WcR, WgS, rbR, CB, OUTS0, pWR, pWhhR, pbR,
                                       (float*)d_out);
}

// Round 9
// 1447.549 us; speedup vs baseline: 3.0502x; 1.0200x over previous
//
#include <hip/hip_runtime.h>
#include <hip/hip_fp8.h>

typedef unsigned short u16;
typedef unsigned char u8;
typedef __attribute__((ext_vector_type(8))) __bf16 bfrag;
typedef long long f8frag;
typedef __attribute__((ext_vector_type(4))) float f32x4;

static __device__ __forceinline__ f32x4 MFMA(bfrag a, bfrag b, f32x4 c) {
  return __builtin_amdgcn_mfma_f32_16x16x32_bf16(a, b, c, 0, 0, 0);
}
static __device__ __forceinline__ f32x4 MFMA8(f8frag a, f8frag b, f32x4 c) {
  return __builtin_amdgcn_mfma_f32_16x16x32_fp8_fp8(a, b, c, 0, 0, 0);
}

// float -> bf16 (RNE)
static __device__ __forceinline__ u16 f2b(float f) {
  union { float f; unsigned u; } v; v.f = f;
  unsigned r = (v.u + 0x7fffu + ((v.u >> 16) & 1u)) >> 16;
  return (u16)r;
}
// float -> fp8 e4m3 (OCP, HW convert)
static __device__ __forceinline__ u8 f2e4m3(float f) {
  return __hip_fp8_e4m3(f).__x;
}
static __device__ __forceinline__ float ssig(float x) { return 1.f / (1.f + __expf(-x)); }
static __device__ __forceinline__ float stanh(float x) { return 1.f - 2.f / (__expf(2.f * x) + 1.f); }

// ---------------------------------------------------------------------------
// prep: bf16/fp8 casts + gate-retiled decode weights.
// Decode: MFMA col n = w*64 + gate*16 + m15 <-> source row gate*256 + w*16 + m15.
// Case 15: Wc8 = combined decode weights in fp8, gate-retiled [1024][256].
// Case 16: Wg8 = g-gate fp8, lane-swizzled for LDS staging:
//   Wg8[((w*8+kt)*64+lane)*8+j] = fp8 of g[hcol=w*16+(lane&15)][k=kt*32+(lane>>4)*8+j]
// Predictor: n' = hcol*4 + gate (cases 12-14), bf16.
// ---------------------------------------------------------------------------
struct PrepArgs {
  const float *x, *W1, *W2, *W3, *Wh1, *Wc1, *Wx1, *Wh2, *Wc2, *Wx2;
  const float *rWih, *rWhh, *rbih, *rbhh, *pWih, *pWhh, *pbih, *pbhh;
  u16 *Xbf, *W1b, *W2b, *W3b, *Wh1b, *Wc1b, *Wx1b, *Wh2b, *Wc2b, *Wx2b;
  u16 *WcatR, *pWR, *pWhhR;
  u8 *Wc8, *Wg8;
  float *rbR, *pbR;
};

__global__ __launch_bounds__(256) void prep(PrepArgs p) {
  const int tid0 = blockIdx.x * 256 + threadIdx.x;
  const int stride = gridDim.x * 256;
  switch (blockIdx.y) {
    case 0: for (int i = tid0; i < 131072; i += stride) p.Xbf[i] = f2b(p.x[i]); break;
    case 1: for (int i = tid0; i < 65536;  i += stride) p.W1b[i] = f2b(p.W1[i]); break;
    case 2: for (int i = tid0; i < 262144; i += stride) p.W2b[i] = f2b(p.W2[i]); break;
    case 3: for (int i = tid0; i < 262144; i += stride) p.W3b[i] = f2b(p.W3[i]); break;
    case 4: for (int i = tid0; i < 262144; i += stride) p.Wh1b[i] = f2b(p.Wh1[i]); break;
    case 5: for (int i = tid0; i < 262144; i += stride) p.Wc1b[i] = f2b(p.Wc1[i]); break;
    case 6: for (int i = tid0; i < 262144; i += stride) p.Wx1b[i] = f2b(p.Wx1[i]); break;
    case 7: for (int i = tid0; i < 131072; i += stride) p.Wh2b[i] = f2b(p.Wh2[i]); break;
    case 8: for (int i = tid0; i < 131072; i += stride) p.Wc2b[i] = f2b(p.Wc2[i]); break;
    case 9: for (int i = tid0; i < 131072; i += stride) p.Wx2b[i] = f2b(p.Wx2[i]); break;
    case 10: // step-0 concat weights (bf16, gate-retiled)
      for (int i = tid0; i < 262144; i += stride) {
        int n = i >> 8, k = i & 255;
        int srow = (((n >> 4) & 3) << 8) + ((n >> 6) << 4) + (n & 15);
        p.WcatR[n * 512 + k] = f2b(p.rWih[srow * 256 + k]);
        p.WcatR[n * 512 + 256 + k] = f2b(p.rWhh[srow * 256 + k]);
      }
      break;
    case 11:
      for (int i = tid0; i < 1024; i += stride) {
        int srow = (((i >> 4) & 3) << 8) + ((i >> 6) << 4) + (i & 15);
        p.rbR[i] = p.rbih[srow] + p.rbhh[srow];
      }
      break;
    case 12:
      for (int i = tid0; i < 32768; i += stride) {
        int n2 = i >> 8, k = i & 255;
        int srow = ((n2 & 3) << 5) + (n2 >> 2);
        p.pWR[i] = f2b(p.pWih[srow * 256 + k]);
      }
      break;
    case 13:
      for (int i = tid0; i < 4096; i += stride) {
        int n2 = i >> 5, k = i & 31;
        int srow = ((n2 & 3) << 5) + (n2 >> 2);
        p.pWhhR[i] = f2b(p.pWhh[srow * 32 + k]);
      }
      break;
    case 14:
      for (int i = tid0; i < 128; i += stride) {
        int srow = ((i & 3) << 5) + (i >> 2);
        p.pbR[i] = p.pbih[srow] + p.pbhh[srow];
      }
      break;
    case 15: // combined decode weights fp8, gate-retiled
      for (int i = tid0; i < 262144; i += stride) {
        int n = i >> 8, k = i & 255;
        int srow = (((n >> 4) & 3) << 8) + ((n >> 6) << 4) + (n & 15);
        p.Wc8[i] = f2e4m3(p.rWih[srow * 256 + k] + p.rWhh[srow * 256 + k]);
      }
      break;
    case 16: // g-gate fp8, lane-swizzled for conflict-free LDS staging
      for (int i = tid0; i < 65536; i += stride) {
        int j = i & 7, lane = (i >> 3) & 63, kt = (i >> 9) & 7, w = i >> 12;
        int srow = 512 + w * 16 + (lane & 15);           // gate g source row
        int k = kt * 32 + (lane >> 4) * 8 + j;
        p.Wg8[i] = f2e4m3(p.rWih[srow * 256 + k] + p.rWhh[srow * 256 + k]);
      }
      break;
  }
}

// ---------------------------------------------------------------------------
// gemm_act: Y[1024,N] = act(X[1024,K] @ W[N,K]^T + bias), bf16 in, fp32 acc.
// ---------------------------------------------------------------------------
__global__ __launch_bounds__(256) void gemm_act(
    const u16* __restrict__ X, const u16* __restrict__ W,
    const float* __restrict__ bias,
    u16* __restrict__ Yb, float* __restrict__ Yf,
    int K, int ldo, int coloff, int leaky) {
  const int rt = blockIdx.x, ct = blockIdx.y;
  const int lane = threadIdx.x & 63, wave = threadIdx.x >> 6;
  const int m15 = lane & 15, q = lane >> 4, kq = q * 8;
  const int row = rt * 64 + wave * 16 + m15;
  f32x4 acc[4] = {};
  const u16* xp = X + (size_t)row * K + kq;
  for (int k0 = 0; k0 < K; k0 += 32) {
    bfrag a = *(const bfrag*)(xp + k0);
#pragma unroll
    for (int nt = 0; nt < 4; nt++) {
      const u16* wp = W + (size_t)(ct * 64 + nt * 16 + m15) * K + k0 + kq;
      acc[nt] = MFMA(a, *(const bfrag*)wp, acc[nt]);
    }
  }
#pragma unroll
  for (int nt = 0; nt < 4; nt++) {
    int col = ct * 64 + nt * 16 + m15;
    float bv = bias[col];
#pragma unroll
    for (int r = 0; r < 4; r++) {
      int orow = rt * 64 + wave * 16 + q * 4 + r;
      float v = acc[nt][r] + bv;
      if (leaky) v = v >= 0.f ? v : 0.2f * v;
      if (Yb) Yb[(size_t)orow * ldo + coloff + col] = f2b(v);
      else    Yf[(size_t)orow * ldo + coloff + col] = v;
    }
  }
}

// ---------------------------------------------------------------------------
// decode_step: step 0 only (K=512 concat input, bf16), gate-retiled columns.
// ---------------------------------------------------------------------------
__global__ __launch_bounds__(256) void decode_step(
    const u16* __restrict__ A, const u16* __restrict__ W,
    const float* __restrict__ rb,
    float* __restrict__ C, u16* __restrict__ Hout, int K) {
  __shared__ float g[64][128];
  const int rt = blockIdx.x, cg = blockIdx.y;
  const int lane = threadIdx.x & 63, wave = threadIdx.x >> 6;
  const int m15 = lane & 15, q = lane >> 4, kq = q * 8;
  const int row = rt * 64 + wave * 16 + m15;
  f32x4 acc[8] = {};
  const u16* ap = A + (size_t)row * K + kq;
  for (int k0 = 0; k0 < K; k0 += 32) {
    bfrag a = *(const bfrag*)(ap + k0);
#pragma unroll
    for (int nt = 0; nt < 8; nt++) {
      const u16* wp = W + (size_t)(cg * 128 + nt * 16 + m15) * K + k0 + kq;
      acc[nt] = MFMA(a, *(const bfrag*)wp, acc[nt]);
    }
  }
#pragma unroll
  for (int nt = 0; nt < 8; nt++)
#pragma unroll
    for (int r = 0; r < 4; r++)
      g[wave * 16 + q * 4 + r][nt * 16 + m15] = acc[nt][r];
  __syncthreads();
  for (int t = threadIdx.x; t < 2048; t += 256) {
    int rl = t >> 5, hc = t & 31;
    int grow = rt * 64 + rl, gcol = cg * 32 + hc;
    int base = ((hc >> 4) << 6) + (hc & 15);
    float gi = g[rl][base +  0] + rb[cg * 128 + base +  0];
    float gf = g[rl][base + 16] + rb[cg * 128 + base + 16];
    float gg = g[rl][base + 32] + rb[cg * 128 + base + 32];
    float go = g[rl][base + 48] + rb[cg * 128 + base + 48];
    size_t ci = (size_t)grow * 256 + gcol;
    float c = C[ci];
    float cn = ssig(gf) * c + ssig(gi) * stanh(gg);
    float hn = ssig(go) * stanh(cn);
    C[ci] = cn;
    Hout[ci] = f2b(hn);
  }
}

// ---------------------------------------------------------------------------
// decode_pred v4 (fp8 decode): 64 blocks x 1024 thr, block = 16 rows x 256
// hcols, zero inter-block sync. R3/R4/R8 showed decode step time is pinned
// at ~20K cyc by a ~26 B/cyc/CU weight-stream law invariant to placement
// tricks -> cut BYTES: decode math in fp8 e4m3 (same fragment geometry as
// bf16 16x16x32). i,f weights = 32 VGPRs (loop-carried pin), g = 64 KB LDS,
// o = streamed fp8 (64 KB/step/CU). Predictor stays bf16 (h enters pred as
// the same bf16 as before; only the decode recurrence takes the fp8 hit).
// h kept in dual LDS: bf16 (pred A-op) + fp8 (decode A-op).
// ---------------------------------------------------------------------------
__global__ __launch_bounds__(1024, 4) void decode_pred(
    const u8* __restrict__ Wc8,     // [1024][256] fp8 gate-retiled (i,f,o)
    const u8* __restrict__ Wg8,     // [65536] swizzled fp8 g-gate
    const float* __restrict__ rb,   // rbR [1024]
    const float* __restrict__ C0,   // CB  [1024][256] (c after step 0)
    const u16* __restrict__ H0,     // h_0 [1024][256] bf16
    const u16* __restrict__ pW,     // pWR  [128][256] bf16
    const u16* __restrict__ pWhh,   // pWhhR [128][32] bf16
    const float* __restrict__ pb,   // pbR [128]
    float* __restrict__ out) {      // [1024][128][32]
  __shared__ u8 wgl8[16][8][512];      // 64 KB fp8 g-gate weights
  __shared__ u16 hbuf[2][16][264];     // 16.9 KB bf16 h (pred)
  __shared__ u8 hbuf8[2][16][272];     // 8.5 KB fp8 h (decode)
  __shared__ float gbuf[8][16][20];    // 10 KB pred transpose
  __shared__ u16 hp[2][16][40];        // 2.5 KB pred hidden
  __shared__ float ys[16][36];         // 2.25 KB
  __shared__ float smv[16], siv[16];
  const int tid = threadIdx.x;
  const int w = tid >> 6, lane = tid & 63;
  const int m15 = lane & 15, q = lane >> 4;
  const int rowg = blockIdx.x * 16;
  const int hc = w * 16 + m15;

  // stage g-gate fp8 weights (one-time, layout == read order)
  for (int i = tid * 8; i < 65536; i += 8192)
    *(unsigned long long*)(&wgl8[0][0][0] + i) = *(const unsigned long long*)(Wg8 + i);
  // h_0: bf16 copy + fp8 conversion
  {
    int r = tid >> 6, c = (tid & 63) * 4;
    const u16* src = H0 + (size_t)(rowg + r) * 256 + c;
    *(unsigned long long*)(&hbuf[0][r][c]) = *(const unsigned long long*)src;
    u8 b4[4];
#pragma unroll
    for (int j = 0; j < 4; j++) {
      union { float f; unsigned u; } v; v.u = (unsigned)src[j] << 16;
      b4[j] = f2e4m3(v.f);
    }
    *(unsigned*)(&hbuf8[0][r][c]) =
        (unsigned)b4[0] | ((unsigned)b4[1] << 8) | ((unsigned)b4[2] << 16) | ((unsigned)b4[3] << 24);
  }
  for (int i = tid; i < 2 * 16 * 40; i += 1024) (&hp[0][0][0])[i] = 0;

  // per-lane decode state
  float cst[4];
#pragma unroll
  for (int r = 0; r < 4; r++)
    cst[r] = C0[(size_t)(rowg + q * 4 + r) * 256 + hc];
  const float rbv0 = rb[w * 64 +  0 + m15], rbv1 = rb[w * 64 + 16 + m15];
  const float rbv2 = rb[w * 64 + 32 + m15], rbv3 = rb[w * 64 + 48 + m15];

  // fp8 weights: row n = w*64 + gate*16 + m15; gate stride = 16 rows = 4096 B
  const u8* wb8 = Wc8 + (size_t)(w * 64 + m15) * 256 + q * 8;
  f8frag WDi8[8], WDf8[8];
#pragma unroll
  for (int kt = 0; kt < 8; kt++) {
    WDi8[kt] = *(const f8frag*)(wb8 + kt * 32);           // gate i (32 VGPRs tot)
    WDf8[kt] = *(const f8frag*)(wb8 + 4096 + kt * 32);    // gate f
  }
  const u8* wo8 = wb8 + 12288;          // gate o, streamed fp8
  const u16* pWl = pW + (size_t)(w * 16 + m15) * 256 + q * 8;   // pred, bf16
  const u16* pWhl = pWhh + (size_t)(w * 16 + m15) * 32 + q * 8;

  // predictor constants (waves 0..7 active)
  const int hloc = lane >> 4, prow = lane & 15;
  const int pcol = w * 4 + hloc;
  const int pc = (w < 8) ? pcol : 0;
  const float pb0 = pb[pc * 4 + 0], pb1 = pb[pc * 4 + 1];
  const float pb2 = pb[pc * 4 + 2], pb3 = pb[pc * 4 + 3];
  float cp = 0.f;
  __syncthreads();

  for (int s = 0; s < 128; s++) {
    if (s) {
      // ---- decode step s (fp8): h_{s-1} -> h_s ----
      const u8* h8 = &hbuf8[(s - 1) & 1][0][0];
      f32x4 ai = {}, af = {}, ag = {}, ao = {};
#pragma unroll
      for (int kt = 0; kt < 8; kt++) {
        // loop-carried pin (only 32 VGPRs of pinned weights now)
        asm volatile("" : "+v"(WDi8[kt]), "+v"(WDf8[kt]));
        f8frag a8 = *(const f8frag*)(h8 + m15 * 272 + kt * 32 + q * 8);
        f8frag bg = *(const f8frag*)(&wgl8[w][kt][0] + lane * 8);
        f8frag bo = *(const f8frag*)(wo8 + kt * 32);
        ai = MFMA8(a8, WDi8[kt], ai);
        af = MFMA8(a8, WDf8[kt], af);
        ag = MFMA8(a8, bg, ag);
        ao = MFMA8(a8, bo, ao);
      }
      u16 hq[4];
      u8 hq8[4];
#pragma unroll
      for (int r = 0; r < 4; r++) {
        float gi = ai[r] + rbv0, gf = af[r] + rbv1;
        float gg = ag[r] + rbv2, go = ao[r] + rbv3;
        float cn = ssig(gf) * cst[r] + ssig(gi) * stanh(gg);
        float hn = ssig(go) * stanh(cn);
        cst[r] = cn;
        hq[r] = f2b(hn);
        hq8[r] = f2e4m3(hn);
      }
      u16* hw = &hbuf[s & 1][0][0];
      u8* hw8 = &hbuf8[s & 1][0][0];
#pragma unroll
      for (int r = 0; r < 4; r++) {
        unsigned mine = hq[r];
        unsigned other = (unsigned)__shfl_xor((int)mine, 1);
        if (!(m15 & 1))
          *(unsigned*)(hw + (q * 4 + r) * 264 + (hc & ~1)) = mine | (other << 16);
        hw8[(q * 4 + r) * 272 + hc] = hq8[r];
      }
      __syncthreads();
    }
    // ---- predictor step s (waves 0..7, bf16) ----
    float hn_p = 0.f;
    if (w < 8) {
      const u16* xr = &hbuf[s & 1][0][0];
      f32x4 pacc = {};
#pragma unroll
      for (int kt = 0; kt < 8; kt++) {
        bfrag a  = *(const bfrag*)(xr + m15 * 264 + kt * 32 + q * 8);
        bfrag bp = *(const bfrag*)(pWl + kt * 32);
        pacc = MFMA(a, bp, pacc);
      }
      {
        bfrag ah = *(const bfrag*)(&hp[s & 1][m15][q * 8]);
        bfrag bh = *(const bfrag*)pWhl;
        pacc = MFMA(ah, bh, pacc);
      }
      *(f32x4*)&gbuf[w][m15][q * 4] = pacc;  // per-wave transpose, in-order DS
      float g0 = gbuf[w][hloc * 4 + 0][prow] + pb0;
      float g1 = gbuf[w][hloc * 4 + 1][prow] + pb1;
      float g2 = gbuf[w][hloc * 4 + 2][prow] + pb2;
      float g3 = gbuf[w][hloc * 4 + 3][prow] + pb3;
      float cn = ssig(g1) * cp + ssig(g0) * stanh(g2);
      hn_p = ssig(g3) * stanh(cn);
      cp = cn;
      hp[(s + 1) & 1][prow][pcol] = f2b(hn_p);
      ys[prow][pcol] = hn_p;
    }
    __syncthreads();
    // ---- softmax stats: 512 threads, half-wave shuffle reduce per row ----
    if (tid < 512) {
      int row_ = tid >> 5, j = tid & 31;
      float v = (j < 31) ? ys[row_][j] : -1e30f;
#pragma unroll
      for (int off = 16; off; off >>= 1) v = fmaxf(v, __shfl_xor(v, off, 32));
      float e = (j < 31) ? __expf(ys[row_][j] - v) : 0.f;
#pragma unroll
      for (int off = 16; off; off >>= 1) e += __shfl_xor(e, off, 32);
      if (j == 0) { smv[row_] = v; siv[row_] = 1.f / e; }
    }
    __syncthreads();
    if (w < 8) {
      float v = (pcol < 31) ? __expf(hn_p - smv[prow]) * siv[prow] : ssig(hn_p);
      out[(size_t)(rowg + prow) * 4096 + s * 32 + pcol] = v;
    }
  }
}

// ---------------------------------------------------------------------------
extern "C" void kernel_launch(void* const* d_in, const int* in_sizes, int n_in,
                              void* d_out, int out_size, void* d_ws, size_t ws_size,
                              hipStream_t stream) {
  (void)in_sizes; (void)n_in; (void)out_size; (void)ws_size;
  const float* x    = (const float*)d_in[0];
  const float* W1   = (const float*)d_in[1];
  const float* b1   = (const float*)d_in[2];
  const float* W2   = (const float*)d_in[3];
  const float* b2   = (const float*)d_in[4];
  const float* W3   = (const float*)d_in[5];
  const float* b3   = (const float*)d_in[6];
  const float* Wh1  = (const float*)d_in[7];
  const float* bh1  = (const float*)d_in[8];
  const float* Wh2  = (const float*)d_in[9];
  const float* bh2  = (const float*)d_in[10];
  const float* Wc1  = (const float*)d_in[11];
  const float* bc1  = (const float*)d_in[12];
  const float* Wc2  = (const float*)d_in[13];
  const float* bc2  = (const float*)d_in[14];
  const float* Wx1  = (const float*)d_in[15];
  const float* bx1  = (const float*)d_in[16];
  const float* Wx2  = (const float*)d_in[17];
  const float* bx2  = (const float*)d_in[18];
  const float* rWih = (const float*)d_in[19];
  const float* rWhh = (const float*)d_in[20];
  const float* rbih = (const float*)d_in[21];
  const float* rbhh = (const float*)d_in[22];
  const float* pWih = (const float*)d_in[23];
  const float* pWhh = (const float*)d_in[24];
  const float* pbih = (const float*)d_in[25];
  const float* pbhh = (const float*)d_in[26];

  char* w = (char*)d_ws;
  auto alloc = [&](size_t bytes) -> char* {
    char* p = w;
    w += (bytes + 255) & ~(size_t)255;
    return p;
  };
  u16* Xbf  = (u16*)alloc(1024 * 128 * 2);
  u16* T1   = (u16*)alloc(1024 * 512 * 2);
  u16* T2   = (u16*)alloc(1024 * 512 * 2);
  u16* T3   = (u16*)alloc(1024 * 512 * 2);
  u16* TH   = (u16*)alloc(1024 * 512 * 2);
  u16* TC   = (u16*)alloc(1024 * 512 * 2);
  u16* TX   = (u16*)alloc(1024 * 512 * 2);
  u16* X0H  = (u16*)alloc(1024 * 512 * 2);  // cols 0..255 = x0, 256..511 = h
  float* CB = (float*)alloc(1024 * 256 * 4);
  u16* OUTS0= (u16*)alloc(1024 * 256 * 2);  // h_0 only
  u16* W1b  = (u16*)alloc(512 * 128 * 2);
  u16* W2b  = (u16*)alloc(512 * 512 * 2);
  u16* W3b  = (u16*)alloc(512 * 512 * 2);
  u16* Wh1b = (u16*)alloc(512 * 512 * 2);
  u16* Wc1b = (u16*)alloc(512 * 512 * 2);
  u16* Wx1b = (u16*)alloc(512 * 512 * 2);
  u16* Wh2b = (u16*)alloc(256 * 512 * 2);
  u16* Wc2b = (u16*)alloc(256 * 512 * 2);
  u16* Wx2b = (u16*)alloc(256 * 512 * 2);
  u16* WcatR= (u16*)alloc(1024 * 512 * 2);
  u8*  Wc8  = (u8*)alloc(1024 * 256);
  u8*  Wg8  = (u8*)alloc(65536);
  float* rbR = (float*)alloc(1024 * 4);
  u16* pWR  = (u16*)alloc(128 * 256 * 2);
  u16* pWhhR= (u16*)alloc(128 * 32 * 2);
  float* pbR = (float*)alloc(128 * 4);

  PrepArgs pa;
  pa.x = x; pa.W1 = W1; pa.W2 = W2; pa.W3 = W3; pa.Wh1 = Wh1; pa.Wc1 = Wc1; pa.Wx1 = Wx1;
  pa.Wh2 = Wh2; pa.Wc2 = Wc2; pa.Wx2 = Wx2;
  pa.rWih = rWih; pa.rWhh = rWhh; pa.rbih = rbih; pa.rbhh = rbhh;
  pa.pWih = pWih; pa.pWhh = pWhh; pa.pbih = pbih; pa.pbhh = pbhh;
  pa.Xbf = Xbf; pa.W1b = W1b; pa.W2b = W2b; pa.W3b = W3b; pa.Wh1b = Wh1b;
  pa.Wc1b = Wc1b; pa.Wx1b = Wx1b; pa.Wh2b = Wh2b; pa.Wc2b = Wc2b; pa.Wx2b = Wx2b;
  pa.WcatR = WcatR; pa.pWR = pWR; pa.pWhhR = pWhhR;
  pa.Wc8 = Wc8; pa.Wg8 = Wg8;
  pa.rbR = rbR; pa.pbR = pbR;
  prep<<<dim3(32, 17), 256, 0, stream>>>(pa);

  // MLP + heads
  gemm_act<<<dim3(16, 8), 256, 0, stream>>>(Xbf, W1b, b1, T1, nullptr, 128, 512, 0, 1);
  gemm_act<<<dim3(16, 8), 256, 0, stream>>>(T1, W2b, b2, T2, nullptr, 512, 512, 0, 1);
  gemm_act<<<dim3(16, 8), 256, 0, stream>>>(T2, W3b, b3, T3, nullptr, 512, 512, 0, 1);
  gemm_act<<<dim3(16, 8), 256, 0, stream>>>(T3, Wh1b, bh1, TH, nullptr, 512, 512, 0, 1);
  gemm_act<<<dim3(16, 8), 256, 0, stream>>>(T3, Wc1b, bc1, TC, nullptr, 512, 512, 0, 1);
  gemm_act<<<dim3(16, 8), 256, 0, stream>>>(T3, Wx1b, bx1, TX, nullptr, 512, 512, 0, 1);
  gemm_act<<<dim3(16, 4), 256, 0, stream>>>(TH, Wh2b, bh2, X0H, nullptr, 512, 512, 256, 0); // h
  gemm_act<<<dim3(16, 4), 256, 0, stream>>>(TC, Wc2b, bc2, nullptr, CB, 512, 256, 0, 0);    // c (fp32)
  gemm_act<<<dim3(16, 4), 256, 0, stream>>>(TX, Wx2b, bx2, X0H, nullptr, 512, 512, 0, 0);   // x0

  // decode step 0 (K=512 concat, bf16), then fused fp8 decode + bf16 pred
  decode_step<<<dim3(16, 8), 256, 0, stream>>>(X0H, WcatR, rbR, CB, OUTS0, 512);
  decode_pred<<<64, 1024, 0, stream>>>(Wc8, Wg8, rbR, CB, OUTS0, pWR, pWhhR, pbR,
                                       (float*)d_out);
}